// Round 1
// baseline (1115.862 us; speedup 1.0000x reference)
//
#include <hip/hip_runtime.h>
#include <hip/hip_bf16.h>
#include <math.h>

#define BM 64
#define BN 64
#define BKK 16

// ---------------- GEMM: C[M,N] = A[M,K] @ B[K,N] (+bias) (+act) ----------------
// act: 0 = none, 2 = sigmoid
__global__ __launch_bounds__(256) void gemm_f32(const float* __restrict__ A,
    const float* __restrict__ B, const float* __restrict__ bias,
    float* __restrict__ C, int M, int N, int K, int act)
{
    __shared__ float As[BKK][BM + 4];   // stride 68: 2-way bank alias (free), 16B aligned
    __shared__ float Bs[BKK][BN + 4];
    const int tid = threadIdx.x;
    const int tx = tid & 15, ty = tid >> 4;
    const int row0 = blockIdx.y * BM, col0 = blockIdx.x * BN;

    float acc[4][4] = {};

    for (int k0 = 0; k0 < K; k0 += BKK) {
        #pragma unroll
        for (int i = 0; i < 4; i++) {
            int idx = tid + i * 256;          // 0..1023
            int am = idx >> 4;                // 0..63
            int ak = idx & 15;
            int gr = row0 + am;
            As[ak][am] = (gr < M) ? A[(size_t)gr * K + k0 + ak] : 0.f;
        }
        #pragma unroll
        for (int i = 0; i < 4; i++) {
            int idx = tid + i * 256;
            int bk = idx >> 6;                // 0..15
            int bn = idx & 63;
            int gc = col0 + bn;
            Bs[bk][bn] = (gc < N) ? B[(size_t)(k0 + bk) * N + gc] : 0.f;
        }
        __syncthreads();
        #pragma unroll
        for (int kk = 0; kk < BKK; kk++) {
            float4 a4 = *(const float4*)&As[kk][ty * 4];
            float4 b4 = *(const float4*)&Bs[kk][tx * 4];
            float av[4] = {a4.x, a4.y, a4.z, a4.w};
            float bv[4] = {b4.x, b4.y, b4.z, b4.w};
            #pragma unroll
            for (int i = 0; i < 4; i++)
                #pragma unroll
                for (int j = 0; j < 4; j++)
                    acc[i][j] += av[i] * bv[j];
        }
        __syncthreads();
    }

    #pragma unroll
    for (int i = 0; i < 4; i++) {
        int r = row0 + ty * 4 + i;
        if (r >= M) continue;
        #pragma unroll
        for (int j = 0; j < 4; j++) {
            int c = col0 + tx * 4 + j;
            if (c >= N) continue;
            float v = acc[i][j] + (bias ? bias[c] : 0.f);
            if (act == 2) v = 1.f / (1.f + expf(-v));
            C[(size_t)r * N + c] = v;
        }
    }
}

// ---------------- CSR build ----------------
__global__ void k_zero(int* __restrict__ p, int n) {
    int i = blockIdx.x * blockDim.x + threadIdx.x;
    if (i < n) p[i] = 0;
}

__global__ void k_count(const int* __restrict__ dstv, int E, int* __restrict__ deg) {
    int e = blockIdx.x * blockDim.x + threadIdx.x;
    if (e < E) atomicAdd(&deg[dstv[e]], 1);
}

__global__ __launch_bounds__(256) void k_scan1(const int* __restrict__ deg, int n,
    int* __restrict__ incl, int* __restrict__ bsum)
{
    __shared__ int s[256];
    int tid = threadIdx.x;
    int i = blockIdx.x * 256 + tid;
    s[tid] = (i < n) ? deg[i] : 0;
    __syncthreads();
    for (int off = 1; off < 256; off <<= 1) {
        int t = (tid >= off) ? s[tid - off] : 0;
        __syncthreads();
        s[tid] += t;
        __syncthreads();
    }
    if (i < n) incl[i] = s[tid];
    if (tid == 255) bsum[blockIdx.x] = s[255];
}

__global__ __launch_bounds__(256) void k_scan2(const int* __restrict__ bsum, int nc,
    int* __restrict__ bscan)
{
    __shared__ int s[256];
    int tid = threadIdx.x;
    s[tid] = (tid < nc) ? bsum[tid] : 0;
    __syncthreads();
    for (int off = 1; off < 256; off <<= 1) {
        int t = (tid >= off) ? s[tid - off] : 0;
        __syncthreads();
        s[tid] += t;
        __syncthreads();
    }
    bscan[tid] = s[tid];
}

__global__ void k_scan3(const int* __restrict__ deg, const int* __restrict__ incl,
    const int* __restrict__ bscan, int n, int* __restrict__ rowptr, int* __restrict__ cursor)
{
    int i = blockIdx.x * blockDim.x + threadIdx.x;
    if (i >= n) return;
    int c = i >> 8;
    int off = (c > 0) ? bscan[c - 1] : 0;
    int inc = incl[i] + off;
    rowptr[i + 1] = inc;
    cursor[i] = inc - deg[i];
    if (i == 0) rowptr[0] = 0;
}

__global__ void k_fill(const int* __restrict__ src, const int* __restrict__ dstv, int E,
    int* __restrict__ cursor, int* __restrict__ eidx, int* __restrict__ colA)
{
    int e = blockIdx.x * blockDim.x + threadIdx.x;
    if (e >= E) return;
    int d = dstv[e];
    int slot = atomicAdd(&cursor[d], 1);
    eidx[slot] = e;
    colA[slot] = src[e];
}

// ---------------- per-edge attention score ----------------
// score[e,h] = att[h] . leaky_relu(xl[src[e],h,:] + xr[dst[e],h,:], 0.2)
__global__ __launch_bounds__(256) void k_score(const float* __restrict__ xl,
    const float* __restrict__ xr, const float* __restrict__ att,
    const int* __restrict__ src, const int* __restrict__ dstv,
    int E, float* __restrict__ score)
{
    int e = blockIdx.x * 4 + (threadIdx.x >> 6);
    int lane = threadIdx.x & 63;
    if (e >= E) return;
    int s = src[e], d = dstv[e];
    float4 a = *(const float4*)&xl[(size_t)s * 256 + lane * 4];
    float4 b = *(const float4*)&xr[(size_t)d * 256 + lane * 4];
    float4 w = *(const float4*)&att[lane * 4];   // [H*C]=256 flat, matches concat layout
    float dot = 0.f;
    {
        float v;
        v = a.x + b.x; v = v > 0.f ? v : 0.2f * v; dot += v * w.x;
        v = a.y + b.y; v = v > 0.f ? v : 0.2f * v; dot += v * w.y;
        v = a.z + b.z; v = v > 0.f ? v : 0.2f * v; dot += v * w.z;
        v = a.w + b.w; v = v > 0.f ? v : 0.2f * v; dot += v * w.w;
    }
    #pragma unroll
    for (int off = 1; off <= 16; off <<= 1) dot += __shfl_xor(dot, off);
    if (lane == 0)  score[2 * (size_t)e]     = dot;
    if (lane == 32) score[2 * (size_t)e + 1] = dot;
}

// ---------------- per-node softmax + aggregation (+bias, +relu) ----------------
__global__ __launch_bounds__(256) void k_agg(const float* __restrict__ xl,
    const float* __restrict__ score, const int* __restrict__ rowptr,
    const int* __restrict__ eidx, const int* __restrict__ colA,
    const float* __restrict__ bias, int Nn, float* __restrict__ outp)
{
    int n = blockIdx.x * 4 + (threadIdx.x >> 6);
    int lane = threadIdx.x & 63;
    if (n >= Nn) return;
    int r0 = rowptr[n], r1 = rowptr[n + 1];

    // pass 1: per-head max
    float m0 = -INFINITY, m1 = -INFINITY;
    for (int s = r0 + lane; s < r1; s += 64) {
        int e = eidx[s];
        float2 sc = *(const float2*)&score[2 * (size_t)e];
        m0 = fmaxf(m0, sc.x); m1 = fmaxf(m1, sc.y);
    }
    #pragma unroll
    for (int off = 32; off; off >>= 1) {
        m0 = fmaxf(m0, __shfl_xor(m0, off));
        m1 = fmaxf(m1, __shfl_xor(m1, off));
    }
    // pass 2: per-head exp-sum
    float l0 = 0.f, l1 = 0.f;
    for (int s = r0 + lane; s < r1; s += 64) {
        int e = eidx[s];
        float2 sc = *(const float2*)&score[2 * (size_t)e];
        l0 += expf(sc.x - m0); l1 += expf(sc.y - m1);
    }
    #pragma unroll
    for (int off = 32; off; off >>= 1) {
        l0 += __shfl_xor(l0, off);
        l1 += __shfl_xor(l1, off);
    }
    const float mmy = (lane < 32) ? m0 : m1;
    const float lmy = ((lane < 32) ? l0 : l1) + 1e-16f;

    // pass 3: weighted aggregation, whole wave walks edges
    float4 acc = {0.f, 0.f, 0.f, 0.f};
    int hsel = (lane >= 32) ? 1 : 0;
    for (int s = r0; s < r1; s++) {
        int e = eidx[s];
        int c = colA[s];
        float sc = score[2 * (size_t)e + hsel];
        float alpha = expf(sc - mmy) / lmy;
        float4 v = *(const float4*)&xl[(size_t)c * 256 + lane * 4];
        acc.x += alpha * v.x; acc.y += alpha * v.y;
        acc.z += alpha * v.z; acc.w += alpha * v.w;
    }
    float4 b4 = *(const float4*)&bias[lane * 4];
    float4 r;
    r.x = fmaxf(acc.x + b4.x, 0.f);
    r.y = fmaxf(acc.y + b4.y, 0.f);
    r.z = fmaxf(acc.z + b4.z, 0.f);
    r.w = fmaxf(acc.w + b4.w, 0.f);
    *(float4*)&outp[(size_t)n * 256 + lane * 4] = r;
}

// ---------------- launch ----------------
extern "C" void kernel_launch(void* const* d_in, const int* in_sizes, int n_in,
                              void* d_out, int out_size, void* d_ws, size_t ws_size,
                              hipStream_t stream)
{
    const float* x    = (const float*)d_in[0];
    const int*   ei   = (const int*)d_in[1];
    const float* Wl1  = (const float*)d_in[2];
    const float* Wr1  = (const float*)d_in[3];
    const float* att1 = (const float*)d_in[4];
    const float* b1   = (const float*)d_in[5];
    const float* Wl2  = (const float*)d_in[6];
    const float* Wr2  = (const float*)d_in[7];
    const float* att2 = (const float*)d_in[8];
    const float* b2   = (const float*)d_in[9];
    const float* W3   = (const float*)d_in[10];
    const float* b3   = (const float*)d_in[11];
    const float* W4   = (const float*)d_in[12];
    const float* b4   = (const float*)d_in[13];

    const int N = in_sizes[0] / 128;       // 50000
    const int E = in_sizes[1] / 2;         // 650000
    const int* src  = ei;
    const int* dstv = ei + E;
    float* out = (float*)d_out;

    // workspace carve-up
    char* ws = (char*)d_ws;
    size_t o = 0;
    auto alloc = [&](size_t bytes) -> void* {
        void* p = ws + o;
        o += (bytes + 255) & ~(size_t)255;
        return p;
    };
    float* bufA  = (float*)alloc((size_t)N * 256 * 4);  // xl
    float* bufB  = (float*)alloc((size_t)N * 256 * 4);  // xr / h3
    float* bufC  = (float*)alloc((size_t)N * 256 * 4);  // h1 / h2
    float* score = (float*)alloc((size_t)E * 2 * 4);
    int* deg    = (int*)alloc((size_t)N * 4);
    int* incl   = (int*)alloc((size_t)N * 4);
    int* rowptr = (int*)alloc((size_t)(N + 1) * 4);
    int* cursor = (int*)alloc((size_t)N * 4);
    int* bsum   = (int*)alloc(1024);
    int* bscan  = (int*)alloc(1024);
    int* eidx   = (int*)alloc((size_t)E * 4);
    int* colA   = (int*)alloc((size_t)E * 4);

    const int nchunk = (N + 255) / 256;    // 196

    // CSR build
    k_zero<<<(N + 255) / 256, 256, 0, stream>>>(deg, N);
    k_count<<<(E + 255) / 256, 256, 0, stream>>>(dstv, E, deg);
    k_scan1<<<nchunk, 256, 0, stream>>>(deg, N, incl, bsum);
    k_scan2<<<1, 256, 0, stream>>>(bsum, nchunk, bscan);
    k_scan3<<<(N + 255) / 256, 256, 0, stream>>>(deg, incl, bscan, N, rowptr, cursor);
    k_fill<<<(E + 255) / 256, 256, 0, stream>>>(src, dstv, E, cursor, eidx, colA);

    dim3 blk(256);
    // Layer 1: xl1 = x@Wl1, xr1 = x@Wr1   [N,128]@[128,256]
    {
        dim3 g((256 + BN - 1) / BN, (N + BM - 1) / BM);
        gemm_f32<<<g, blk, 0, stream>>>(x, Wl1, nullptr, bufA, N, 256, 128, 0);
        gemm_f32<<<g, blk, 0, stream>>>(x, Wr1, nullptr, bufB, N, 256, 128, 0);
    }
    k_score<<<(E + 3) / 4, blk, 0, stream>>>(bufA, bufB, att1, src, dstv, E, score);
    k_agg<<<(N + 3) / 4, blk, 0, stream>>>(bufA, score, rowptr, eidx, colA, b1, N, bufC);

    // Layer 2: xl2 = h1@Wl2, xr2 = h1@Wr2  [N,256]@[256,256]
    {
        dim3 g((256 + BN - 1) / BN, (N + BM - 1) / BM);
        gemm_f32<<<g, blk, 0, stream>>>(bufC, Wl2, nullptr, bufA, N, 256, 256, 0);
        gemm_f32<<<g, blk, 0, stream>>>(bufC, Wr2, nullptr, bufB, N, 256, 256, 0);
    }
    k_score<<<(E + 3) / 4, blk, 0, stream>>>(bufA, bufB, att2, src, dstv, E, score);
    k_agg<<<(N + 3) / 4, blk, 0, stream>>>(bufA, score, rowptr, eidx, colA, b2, N, bufC);

    // h3 = h2@W3 + b3   [N,256]@[256,128]
    {
        dim3 g((128 + BN - 1) / BN, (N + BM - 1) / BM);
        gemm_f32<<<g, blk, 0, stream>>>(bufC, W3, b3, bufB, N, 128, 256, 0);
    }
    // out = sigmoid(h3@W4 + b4)  [N,128]@[128,40]
    {
        dim3 g((40 + BN - 1) / BN, (N + BM - 1) / BM);
        gemm_f32<<<g, blk, 0, stream>>>(bufB, W4, b4, out, N, 40, 128, 2);
    }
}

// Round 2
// 746.852 us; speedup vs baseline: 1.4941x; 1.4941x over previous
//
#include <hip/hip_runtime.h>
#include <hip/hip_bf16.h>
#include <math.h>

#define BM 64
#define BN 64
#define BKK 16

// ---------------- GEMM: C[M,N] = A[M,K] @ B[K,N] (+bias) (+act) ----------------
// act: 0 = none, 2 = sigmoid
__global__ __launch_bounds__(256) void gemm_f32(const float* __restrict__ A,
    const float* __restrict__ B, const float* __restrict__ bias,
    float* __restrict__ C, int M, int N, int K, int act)
{
    __shared__ float As[BKK][BM + 4];
    __shared__ float Bs[BKK][BN + 4];
    const int tid = threadIdx.x;
    const int tx = tid & 15, ty = tid >> 4;
    const int row0 = blockIdx.y * BM, col0 = blockIdx.x * BN;

    float acc[4][4] = {};

    for (int k0 = 0; k0 < K; k0 += BKK) {
        #pragma unroll
        for (int i = 0; i < 4; i++) {
            int idx = tid + i * 256;          // 0..1023
            int am = idx >> 4;                // 0..63
            int ak = idx & 15;
            int gr = row0 + am;
            As[ak][am] = (gr < M) ? A[(size_t)gr * K + k0 + ak] : 0.f;
        }
        #pragma unroll
        for (int i = 0; i < 4; i++) {
            int idx = tid + i * 256;
            int bk = idx >> 6;                // 0..15
            int bn = idx & 63;
            int gc = col0 + bn;
            Bs[bk][bn] = (gc < N) ? B[(size_t)(k0 + bk) * N + gc] : 0.f;
        }
        __syncthreads();
        #pragma unroll
        for (int kk = 0; kk < BKK; kk++) {
            float4 a4 = *(const float4*)&As[kk][ty * 4];
            float4 b4 = *(const float4*)&Bs[kk][tx * 4];
            float av[4] = {a4.x, a4.y, a4.z, a4.w};
            float bv[4] = {b4.x, b4.y, b4.z, b4.w};
            #pragma unroll
            for (int i = 0; i < 4; i++)
                #pragma unroll
                for (int j = 0; j < 4; j++)
                    acc[i][j] += av[i] * bv[j];
        }
        __syncthreads();
    }

    #pragma unroll
    for (int i = 0; i < 4; i++) {
        int r = row0 + ty * 4 + i;
        if (r >= M) continue;
        #pragma unroll
        for (int j = 0; j < 4; j++) {
            int c = col0 + tx * 4 + j;
            if (c >= N) continue;
            float v = acc[i][j] + (bias ? bias[c] : 0.f);
            if (act == 2) v = 1.f / (1.f + expf(-v));
            C[(size_t)r * N + c] = v;
        }
    }
}

// ---------------- CSR build ----------------
__global__ void k_zero(int* __restrict__ p, int n) {
    int i = blockIdx.x * blockDim.x + threadIdx.x;
    if (i < n) p[i] = 0;
}

__global__ void k_count(const int* __restrict__ dstv, int E, int* __restrict__ deg) {
    int e = blockIdx.x * blockDim.x + threadIdx.x;
    if (e < E) atomicAdd(&deg[dstv[e]], 1);
}

__global__ __launch_bounds__(256) void k_scan1(const int* __restrict__ deg, int n,
    int* __restrict__ incl, int* __restrict__ bsum)
{
    __shared__ int s[256];
    int tid = threadIdx.x;
    int i = blockIdx.x * 256 + tid;
    s[tid] = (i < n) ? deg[i] : 0;
    __syncthreads();
    for (int off = 1; off < 256; off <<= 1) {
        int t = (tid >= off) ? s[tid - off] : 0;
        __syncthreads();
        s[tid] += t;
        __syncthreads();
    }
    if (i < n) incl[i] = s[tid];
    if (tid == 255) bsum[blockIdx.x] = s[255];
}

__global__ __launch_bounds__(256) void k_scan2(const int* __restrict__ bsum, int nc,
    int* __restrict__ bscan)
{
    __shared__ int s[256];
    int tid = threadIdx.x;
    s[tid] = (tid < nc) ? bsum[tid] : 0;
    __syncthreads();
    for (int off = 1; off < 256; off <<= 1) {
        int t = (tid >= off) ? s[tid - off] : 0;
        __syncthreads();
        s[tid] += t;
        __syncthreads();
    }
    bscan[tid] = s[tid];
}

__global__ void k_scan3(const int* __restrict__ deg, const int* __restrict__ incl,
    const int* __restrict__ bscan, int n, int* __restrict__ rowptr, int* __restrict__ cursor)
{
    int i = blockIdx.x * blockDim.x + threadIdx.x;
    if (i >= n) return;
    int c = i >> 8;
    int off = (c > 0) ? bscan[c - 1] : 0;
    int inc = incl[i] + off;
    rowptr[i + 1] = inc;
    cursor[i] = inc - deg[i];
    if (i == 0) rowptr[0] = 0;
}

__global__ void k_fill(const int* __restrict__ src, const int* __restrict__ dstv, int E,
    int* __restrict__ cursor, int* __restrict__ colA)
{
    int e = blockIdx.x * blockDim.x + threadIdx.x;
    if (e >= E) return;
    int d = dstv[e];
    int slot = atomicAdd(&cursor[d], 1);
    colA[slot] = src[e];
}

// ---------------- fused attention: score + online softmax + aggregation ----------------
// One wave per dst node. xr[dst] and att held in registers; single pass over
// incoming edges: gather xl[src] row once, leakyrelu-dot (per-head shuffle
// reduce), branchless online-softmax accumulate. Output = relu(acc/l + bias).
__global__ __launch_bounds__(256) void k_attn(const float* __restrict__ xl,
    const float* __restrict__ xr, const float* __restrict__ att,
    const int* __restrict__ rowptr, const int* __restrict__ colA,
    const float* __restrict__ bias, int Nn, float* __restrict__ outp)
{
    int n = blockIdx.x * 4 + (threadIdx.x >> 6);
    int lane = threadIdx.x & 63;
    if (n >= Nn) return;
    int r0 = rowptr[n], r1 = rowptr[n + 1];

    float4 xrv = *(const float4*)&xr[(size_t)n * 256 + lane * 4];
    float4 w   = *(const float4*)&att[lane * 4];   // att flat [H*C]=256

    float m = -INFINITY, l = 0.f;
    float4 acc = {0.f, 0.f, 0.f, 0.f};

    for (int s = r0; s < r1; s++) {
        int c = colA[s];
        float4 v = *(const float4*)&xl[(size_t)c * 256 + lane * 4];
        float t, dot = 0.f;
        t = v.x + xrv.x; t = t > 0.f ? t : 0.2f * t; dot += t * w.x;
        t = v.y + xrv.y; t = t > 0.f ? t : 0.2f * t; dot += t * w.y;
        t = v.z + xrv.z; t = t > 0.f ? t : 0.2f * t; dot += t * w.z;
        t = v.w + xrv.w; t = t > 0.f ? t : 0.2f * t; dot += t * w.w;
        #pragma unroll
        for (int off = 1; off <= 16; off <<= 1) dot += __shfl_xor(dot, off);
        // dot now uniform within each 32-lane half (head 0 = lanes 0..31, head 1 = 32..63)

        float mn = fmaxf(m, dot);
        float sc = __expf(m - mn);     // ==1 when no new max; ==0 on first iter (m=-inf)
        float we = __expf(dot - mn);
        l = l * sc + we;
        acc.x = acc.x * sc + we * v.x;
        acc.y = acc.y * sc + we * v.y;
        acc.z = acc.z * sc + we * v.z;
        acc.w = acc.w * sc + we * v.w;
        m = mn;
    }

    float inv = 1.f / (l + 1e-16f);
    float4 b4 = *(const float4*)&bias[lane * 4];
    float4 r;
    r.x = fmaxf(acc.x * inv + b4.x, 0.f);
    r.y = fmaxf(acc.y * inv + b4.y, 0.f);
    r.z = fmaxf(acc.z * inv + b4.z, 0.f);
    r.w = fmaxf(acc.w * inv + b4.w, 0.f);
    *(float4*)&outp[(size_t)n * 256 + lane * 4] = r;
}

// ---------------- launch ----------------
extern "C" void kernel_launch(void* const* d_in, const int* in_sizes, int n_in,
                              void* d_out, int out_size, void* d_ws, size_t ws_size,
                              hipStream_t stream)
{
    const float* x    = (const float*)d_in[0];
    const int*   ei   = (const int*)d_in[1];
    const float* Wl1  = (const float*)d_in[2];
    const float* Wr1  = (const float*)d_in[3];
    const float* att1 = (const float*)d_in[4];
    const float* b1   = (const float*)d_in[5];
    const float* Wl2  = (const float*)d_in[6];
    const float* Wr2  = (const float*)d_in[7];
    const float* att2 = (const float*)d_in[8];
    const float* b2   = (const float*)d_in[9];
    const float* W3   = (const float*)d_in[10];
    const float* b3   = (const float*)d_in[11];
    const float* W4   = (const float*)d_in[12];
    const float* b4   = (const float*)d_in[13];

    const int N = in_sizes[0] / 128;       // 50000
    const int E = in_sizes[1] / 2;         // 650000
    const int* src  = ei;
    const int* dstv = ei + E;
    float* out = (float*)d_out;

    // workspace carve-up
    char* ws = (char*)d_ws;
    size_t o = 0;
    auto alloc = [&](size_t bytes) -> void* {
        void* p = ws + o;
        o += (bytes + 255) & ~(size_t)255;
        return p;
    };
    float* bufA  = (float*)alloc((size_t)N * 256 * 4);  // xl
    float* bufB  = (float*)alloc((size_t)N * 256 * 4);  // xr / h3
    float* bufC  = (float*)alloc((size_t)N * 256 * 4);  // h1 / h2
    int* deg    = (int*)alloc((size_t)N * 4);
    int* incl   = (int*)alloc((size_t)N * 4);
    int* rowptr = (int*)alloc((size_t)(N + 1) * 4);
    int* cursor = (int*)alloc((size_t)N * 4);
    int* bsum   = (int*)alloc(1024);
    int* bscan  = (int*)alloc(1024);
    int* colA   = (int*)alloc((size_t)E * 4);

    const int nchunk = (N + 255) / 256;    // 196

    // CSR build (by dst)
    k_zero<<<(N + 255) / 256, 256, 0, stream>>>(deg, N);
    k_count<<<(E + 255) / 256, 256, 0, stream>>>(dstv, E, deg);
    k_scan1<<<nchunk, 256, 0, stream>>>(deg, N, incl, bsum);
    k_scan2<<<1, 256, 0, stream>>>(bsum, nchunk, bscan);
    k_scan3<<<(N + 255) / 256, 256, 0, stream>>>(deg, incl, bscan, N, rowptr, cursor);
    k_fill<<<(E + 255) / 256, 256, 0, stream>>>(src, dstv, E, cursor, colA);

    dim3 blk(256);
    // Layer 1: xl1 = x@Wl1, xr1 = x@Wr1   [N,128]@[128,256]
    {
        dim3 g((256 + BN - 1) / BN, (N + BM - 1) / BM);
        gemm_f32<<<g, blk, 0, stream>>>(x, Wl1, nullptr, bufA, N, 256, 128, 0);
        gemm_f32<<<g, blk, 0, stream>>>(x, Wr1, nullptr, bufB, N, 256, 128, 0);
    }
    k_attn<<<(N + 3) / 4, blk, 0, stream>>>(bufA, bufB, att1, rowptr, colA, b1, N, bufC);

    // Layer 2: xl2 = h1@Wl2, xr2 = h1@Wr2  [N,256]@[256,256]
    {
        dim3 g((256 + BN - 1) / BN, (N + BM - 1) / BM);
        gemm_f32<<<g, blk, 0, stream>>>(bufC, Wl2, nullptr, bufA, N, 256, 256, 0);
        gemm_f32<<<g, blk, 0, stream>>>(bufC, Wr2, nullptr, bufB, N, 256, 256, 0);
    }
    k_attn<<<(N + 3) / 4, blk, 0, stream>>>(bufA, bufB, att2, rowptr, colA, b2, N, bufC);

    // h3 = h2@W3 + b3   [N,256]@[256,128]
    {
        dim3 g((128 + BN - 1) / BN, (N + BM - 1) / BM);
        gemm_f32<<<g, blk, 0, stream>>>(bufC, W3, b3, bufB, N, 128, 256, 0);
    }
    // out = sigmoid(h3@W4 + b4)  [N,128]@[128,40]
    {
        dim3 g((40 + BN - 1) / BN, (N + BM - 1) / BM);
        gemm_f32<<<g, blk, 0, stream>>>(bufB, W4, b4, out, N, 40, 128, 2);
    }
}

// Round 3
// 389.278 us; speedup vs baseline: 2.8665x; 1.9186x over previous
//
#include <hip/hip_runtime.h>
#include <hip/hip_bf16.h>
#include <math.h>

typedef __attribute__((ext_vector_type(4))) float f32x4;
typedef __attribute__((ext_vector_type(8))) short s16x8;

__device__ inline unsigned short f2b(float f) {
    union { float f; unsigned u; } x; x.f = f;
    unsigned r = x.u + 0x7FFF + ((x.u >> 16) & 1);   // RNE
    return (unsigned short)(r >> 16);
}
__device__ inline float b2f(unsigned short b) {
    union { unsigned u; float f; } x; x.u = ((unsigned)b) << 16; return x.f;
}

__device__ inline void gload_lds16(const void* g, void* l) {
    __builtin_amdgcn_global_load_lds(
        (const __attribute__((address_space(1))) void*)g,
        (__attribute__((address_space(3))) void*)l, 16, 0, 0);
}

// ---------------- bf16 MFMA GEMM ----------------
// A [M,K] bf16 row-major, Bt [N,K] bf16 row-major (B pre-transposed).
// mode 0: out bf16 [M,N], no bias. mode 1: out f32 [M,N], + bias.
// Tile 128x128, BK=64, 4 waves in 2x2, each wave 64x64 via 4x4 frags of 16x16x32.
// LDS linear (global_load_lds), bank-swizzle via pre-swizzled GLOBAL source:
// slot L holds global chunk (row=L>>3, c=(L&7)^(row&7)); reader XORs the same.
#define GBM 128
#define GBN 128
#define GBK 64

__global__ __launch_bounds__(256) void gemm_mfma(
    const unsigned short* __restrict__ A, const unsigned short* __restrict__ Bt,
    const float* __restrict__ bias, void* __restrict__ Cout,
    int M, int Nn, int K, int mode)
{
    __shared__ unsigned short As[GBM * GBK];
    __shared__ unsigned short Bs[GBN * GBK];
    const int tid = threadIdx.x;
    const int lane = tid & 63;
    const int w = tid >> 6, wm = w >> 1, wn = w & 1;
    const int row0 = blockIdx.y * GBM, col0 = blockIdx.x * GBN;
    const int l15 = lane & 15, l7 = lane & 7, lhi = lane >> 4;

    f32x4 acc[4][4] = {};

    for (int k0 = 0; k0 < K; k0 += GBK) {
        #pragma unroll
        for (int i = 0; i < 4; i++) {               // A: 1024 chunks of 16B
            int L = i * 256 + tid;
            int row = L >> 3;
            int c = (L & 7) ^ (row & 7);
            int gr = row0 + row; gr = gr < M ? gr : M - 1;
            gload_lds16(A + (size_t)gr * K + k0 + c * 8, (char*)As + L * 16);
        }
        #pragma unroll
        for (int i = 0; i < 4; i++) {               // B: 1024 chunks
            int L = i * 256 + tid;
            int row = L >> 3;
            int c = (L & 7) ^ (row & 7);
            gload_lds16(Bt + (size_t)(col0 + row) * K + k0 + c * 8, (char*)Bs + L * 16);
        }
        __syncthreads();                            // drains vmcnt too
        #pragma unroll
        for (int kk = 0; kk < 2; kk++) {
            s16x8 af[4], bf[4];
            #pragma unroll
            for (int i = 0; i < 4; i++) {
                int slot = (wm * 64 + i * 16 + l15) * 8 + ((kk * 4 + lhi) ^ l7);
                af[i] = *(const s16x8*)((const char*)As + slot * 16);
            }
            #pragma unroll
            for (int j = 0; j < 4; j++) {
                int slot = (wn * 64 + j * 16 + l15) * 8 + ((kk * 4 + lhi) ^ l7);
                bf[j] = *(const s16x8*)((const char*)Bs + slot * 16);
            }
            #pragma unroll
            for (int i = 0; i < 4; i++)
                #pragma unroll
                for (int j = 0; j < 4; j++)
                    acc[i][j] = __builtin_amdgcn_mfma_f32_16x16x32_bf16(
                        af[i], bf[j], acc[i][j], 0, 0, 0);
        }
        __syncthreads();
    }

    // epilogue: C/D layout col=lane&15, row=(lane>>4)*4+reg (m89-verified)
    if (mode == 0) {
        unsigned short* C = (unsigned short*)Cout;
        #pragma unroll
        for (int i = 0; i < 4; i++)
            #pragma unroll
            for (int r = 0; r < 4; r++) {
                int row = row0 + wm * 64 + i * 16 + lhi * 4 + r;
                if (row >= M) continue;
                #pragma unroll
                for (int j = 0; j < 4; j++) {
                    int col = col0 + wn * 64 + j * 16 + l15;
                    C[(size_t)row * Nn + col] = f2b(acc[i][j][r]);
                }
            }
    } else {
        float* C = (float*)Cout;
        #pragma unroll
        for (int i = 0; i < 4; i++)
            #pragma unroll
            for (int r = 0; r < 4; r++) {
                int row = row0 + wm * 64 + i * 16 + lhi * 4 + r;
                if (row >= M) continue;
                #pragma unroll
                for (int j = 0; j < 4; j++) {
                    int col = col0 + wn * 64 + j * 16 + l15;
                    C[(size_t)row * Nn + col] = acc[i][j][r] + bias[col];
                }
            }
    }
}

// ---------------- f32 GEMM (only for final W4, N=40) ----------------
#define BM 64
#define BN 64
#define BKK 16
__global__ __launch_bounds__(256) void gemm_f32(const float* __restrict__ A,
    const float* __restrict__ B, const float* __restrict__ bias,
    float* __restrict__ C, int M, int N, int K, int act)
{
    __shared__ float As[BKK][BM + 4];
    __shared__ float Bs[BKK][BN + 4];
    const int tid = threadIdx.x;
    const int tx = tid & 15, ty = tid >> 4;
    const int row0 = blockIdx.y * BM, col0 = blockIdx.x * BN;

    float acc[4][4] = {};

    for (int k0 = 0; k0 < K; k0 += BKK) {
        #pragma unroll
        for (int i = 0; i < 4; i++) {
            int idx = tid + i * 256;
            int am = idx >> 4;
            int ak = idx & 15;
            int gr = row0 + am;
            As[ak][am] = (gr < M) ? A[(size_t)gr * K + k0 + ak] : 0.f;
        }
        #pragma unroll
        for (int i = 0; i < 4; i++) {
            int idx = tid + i * 256;
            int bk = idx >> 6;
            int bn = idx & 63;
            int gc = col0 + bn;
            Bs[bk][bn] = (gc < N) ? B[(size_t)(k0 + bk) * N + gc] : 0.f;
        }
        __syncthreads();
        #pragma unroll
        for (int kk = 0; kk < BKK; kk++) {
            float4 a4 = *(const float4*)&As[kk][ty * 4];
            float4 b4 = *(const float4*)&Bs[kk][tx * 4];
            float av[4] = {a4.x, a4.y, a4.z, a4.w};
            float bv[4] = {b4.x, b4.y, b4.z, b4.w};
            #pragma unroll
            for (int i = 0; i < 4; i++)
                #pragma unroll
                for (int j = 0; j < 4; j++)
                    acc[i][j] += av[i] * bv[j];
        }
        __syncthreads();
    }

    #pragma unroll
    for (int i = 0; i < 4; i++) {
        int r = row0 + ty * 4 + i;
        if (r >= M) continue;
        #pragma unroll
        for (int j = 0; j < 4; j++) {
            int c = col0 + tx * 4 + j;
            if (c >= N) continue;
            float v = acc[i][j] + (bias ? bias[c] : 0.f);
            if (act == 2) v = 1.f / (1.f + expf(-v));
            C[(size_t)r * N + c] = v;
        }
    }
}

// ---------------- conversions ----------------
__global__ void k_cvt(const float* __restrict__ in, unsigned short* __restrict__ out, int n) {
    int i = blockIdx.x * 256 + threadIdx.x;
    if (i < n) out[i] = f2b(in[i]);
}
// out[n*K+k] = bf16(in[k*N+n])  (weight [K,N] -> [N,K] bf16)
__global__ void k_cvt_t(const float* __restrict__ in, unsigned short* __restrict__ out,
                        int K, int N) {
    int i = blockIdx.x * 256 + threadIdx.x;
    if (i >= K * N) return;
    int n = i / K, k = i - n * K;
    out[i] = f2b(in[(size_t)k * N + n]);
}

// ---------------- CSR build ----------------
__global__ void k_zero(int* __restrict__ p, int n) {
    int i = blockIdx.x * blockDim.x + threadIdx.x;
    if (i < n) p[i] = 0;
}
__global__ void k_count(const int* __restrict__ dstv, int E, int* __restrict__ deg) {
    int e = blockIdx.x * blockDim.x + threadIdx.x;
    if (e < E) atomicAdd(&deg[dstv[e]], 1);
}
__global__ __launch_bounds__(256) void k_scan1(const int* __restrict__ deg, int n,
    int* __restrict__ incl, int* __restrict__ bsum)
{
    __shared__ int s[256];
    int tid = threadIdx.x;
    int i = blockIdx.x * 256 + tid;
    s[tid] = (i < n) ? deg[i] : 0;
    __syncthreads();
    for (int off = 1; off < 256; off <<= 1) {
        int t = (tid >= off) ? s[tid - off] : 0;
        __syncthreads();
        s[tid] += t;
        __syncthreads();
    }
    if (i < n) incl[i] = s[tid];
    if (tid == 255) bsum[blockIdx.x] = s[255];
}
__global__ __launch_bounds__(256) void k_scan2(const int* __restrict__ bsum, int nc,
    int* __restrict__ bscan)
{
    __shared__ int s[256];
    int tid = threadIdx.x;
    s[tid] = (tid < nc) ? bsum[tid] : 0;
    __syncthreads();
    for (int off = 1; off < 256; off <<= 1) {
        int t = (tid >= off) ? s[tid - off] : 0;
        __syncthreads();
        s[tid] += t;
        __syncthreads();
    }
    bscan[tid] = s[tid];
}
__global__ void k_scan3(const int* __restrict__ deg, const int* __restrict__ incl,
    const int* __restrict__ bscan, int n, int* __restrict__ rowptr, int* __restrict__ cursor)
{
    int i = blockIdx.x * blockDim.x + threadIdx.x;
    if (i >= n) return;
    int c = i >> 8;
    int off = (c > 0) ? bscan[c - 1] : 0;
    int inc = incl[i] + off;
    rowptr[i + 1] = inc;
    cursor[i] = inc - deg[i];
    if (i == 0) rowptr[0] = 0;
}
__global__ void k_fill(const int* __restrict__ src, const int* __restrict__ dstv, int E,
    int* __restrict__ cursor, int* __restrict__ colA)
{
    int e = blockIdx.x * blockDim.x + threadIdx.x;
    if (e >= E) return;
    int d = dstv[e];
    int slot = atomicAdd(&cursor[d], 1);
    colA[slot] = src[e];
}

// ---------------- fused attention (bf16 tables, f32 math) ----------------
__global__ __launch_bounds__(256) void k_attn(const unsigned short* __restrict__ xl,
    const unsigned short* __restrict__ xr, const float* __restrict__ att,
    const int* __restrict__ rowptr, const int* __restrict__ colA,
    const float* __restrict__ bias, int Nn, unsigned short* __restrict__ outp)
{
    int n = blockIdx.x * 4 + (threadIdx.x >> 6);
    int lane = threadIdx.x & 63;
    if (n >= Nn) return;
    int r0 = rowptr[n], r1 = rowptr[n + 1];

    ushort4 xb = *(const ushort4*)&xr[(size_t)n * 256 + lane * 4];
    float4 xrv = {b2f(xb.x), b2f(xb.y), b2f(xb.z), b2f(xb.w)};
    float4 w = *(const float4*)&att[lane * 4];   // att flat [H*C]=256

    float m = -INFINITY, l = 0.f;
    float4 acc = {0.f, 0.f, 0.f, 0.f};

    for (int s = r0; s < r1; s++) {
        int c = colA[s];
        ushort4 vb = *(const ushort4*)&xl[(size_t)c * 256 + lane * 4];
        float4 v = {b2f(vb.x), b2f(vb.y), b2f(vb.z), b2f(vb.w)};
        float t, dot = 0.f;
        t = v.x + xrv.x; t = t > 0.f ? t : 0.2f * t; dot += t * w.x;
        t = v.y + xrv.y; t = t > 0.f ? t : 0.2f * t; dot += t * w.y;
        t = v.z + xrv.z; t = t > 0.f ? t : 0.2f * t; dot += t * w.z;
        t = v.w + xrv.w; t = t > 0.f ? t : 0.2f * t; dot += t * w.w;
        #pragma unroll
        for (int off = 1; off <= 16; off <<= 1) dot += __shfl_xor(dot, off);
        // dot uniform within each 32-lane half (head0 = lanes 0..31, head1 = 32..63)

        float mn = fmaxf(m, dot);
        float sc = __expf(m - mn);
        float we = __expf(dot - mn);
        l = l * sc + we;
        acc.x = acc.x * sc + we * v.x;
        acc.y = acc.y * sc + we * v.y;
        acc.z = acc.z * sc + we * v.z;
        acc.w = acc.w * sc + we * v.w;
        m = mn;
    }

    float inv = 1.f / (l + 1e-16f);
    float4 b4 = *(const float4*)&bias[lane * 4];
    ushort4 o;
    o.x = f2b(fmaxf(acc.x * inv + b4.x, 0.f));
    o.y = f2b(fmaxf(acc.y * inv + b4.y, 0.f));
    o.z = f2b(fmaxf(acc.z * inv + b4.z, 0.f));
    o.w = f2b(fmaxf(acc.w * inv + b4.w, 0.f));
    *(ushort4*)&outp[(size_t)n * 256 + lane * 4] = o;
}

// ---------------- launch ----------------
extern "C" void kernel_launch(void* const* d_in, const int* in_sizes, int n_in,
                              void* d_out, int out_size, void* d_ws, size_t ws_size,
                              hipStream_t stream)
{
    const float* x    = (const float*)d_in[0];
    const int*   ei   = (const int*)d_in[1];
    const float* Wl1  = (const float*)d_in[2];
    const float* Wr1  = (const float*)d_in[3];
    const float* att1 = (const float*)d_in[4];
    const float* b1   = (const float*)d_in[5];
    const float* Wl2  = (const float*)d_in[6];
    const float* Wr2  = (const float*)d_in[7];
    const float* att2 = (const float*)d_in[8];
    const float* b2   = (const float*)d_in[9];
    const float* W3   = (const float*)d_in[10];
    const float* b3   = (const float*)d_in[11];
    const float* W4   = (const float*)d_in[12];
    const float* b4   = (const float*)d_in[13];

    const int N = in_sizes[0] / 128;       // 50000
    const int E = in_sizes[1] / 2;         // 650000
    const int* src  = ei;
    const int* dstv = ei + E;
    float* out = (float*)d_out;

    char* ws = (char*)d_ws;
    size_t o = 0;
    auto alloc = [&](size_t bytes) -> void* {
        void* p = ws + o;
        o += (bytes + 255) & ~(size_t)255;
        return p;
    };
    unsigned short* xbf   = (unsigned short*)alloc((size_t)N * 128 * 2);
    unsigned short* Wl1t  = (unsigned short*)alloc(256 * 128 * 2);
    unsigned short* Wr1t  = (unsigned short*)alloc(256 * 128 * 2);
    unsigned short* Wl2t  = (unsigned short*)alloc(256 * 256 * 2);
    unsigned short* Wr2t  = (unsigned short*)alloc(256 * 256 * 2);
    unsigned short* W3t   = (unsigned short*)alloc(128 * 256 * 2);
    unsigned short* xlb   = (unsigned short*)alloc((size_t)N * 256 * 2);
    unsigned short* xrb   = (unsigned short*)alloc((size_t)N * 256 * 2);
    unsigned short* h1b   = (unsigned short*)alloc((size_t)N * 256 * 2);
    unsigned short* h2b   = (unsigned short*)alloc((size_t)N * 256 * 2);
    float*          h3f   = (float*)alloc((size_t)N * 128 * 4);
    int* deg    = (int*)alloc((size_t)N * 4);
    int* incl   = (int*)alloc((size_t)N * 4);
    int* rowptr = (int*)alloc((size_t)(N + 1) * 4);
    int* cursor = (int*)alloc((size_t)N * 4);
    int* bsum   = (int*)alloc(1024);
    int* bscan  = (int*)alloc(1024);
    int* colA   = (int*)alloc((size_t)E * 4);

    const int nchunk = (N + 255) / 256;    // 196
    dim3 blk(256);

    // conversions
    k_cvt<<<(N * 128 + 255) / 256, blk, 0, stream>>>(x, xbf, N * 128);
    k_cvt_t<<<(128 * 256 + 255) / 256, blk, 0, stream>>>(Wl1, Wl1t, 128, 256);
    k_cvt_t<<<(128 * 256 + 255) / 256, blk, 0, stream>>>(Wr1, Wr1t, 128, 256);
    k_cvt_t<<<(256 * 256 + 255) / 256, blk, 0, stream>>>(Wl2, Wl2t, 256, 256);
    k_cvt_t<<<(256 * 256 + 255) / 256, blk, 0, stream>>>(Wr2, Wr2t, 256, 256);
    k_cvt_t<<<(256 * 128 + 255) / 256, blk, 0, stream>>>(W3, W3t, 256, 128);

    // CSR build (by dst)
    k_zero<<<(N + 255) / 256, blk, 0, stream>>>(deg, N);
    k_count<<<(E + 255) / 256, blk, 0, stream>>>(dstv, E, deg);
    k_scan1<<<nchunk, blk, 0, stream>>>(deg, N, incl, bsum);
    k_scan2<<<1, blk, 0, stream>>>(bsum, nchunk, bscan);
    k_scan3<<<(N + 255) / 256, blk, 0, stream>>>(deg, incl, bscan, N, rowptr, cursor);
    k_fill<<<(E + 255) / 256, blk, 0, stream>>>(src, dstv, E, cursor, colA);

    const int gy = (N + GBM - 1) / GBM;    // 391

    // Layer 1: [N,128]@[128,256]
    gemm_mfma<<<dim3(2, gy), blk, 0, stream>>>(xbf, Wl1t, nullptr, xlb, N, 256, 128, 0);
    gemm_mfma<<<dim3(2, gy), blk, 0, stream>>>(xbf, Wr1t, nullptr, xrb, N, 256, 128, 0);
    k_attn<<<(N + 3) / 4, blk, 0, stream>>>(xlb, xrb, att1, rowptr, colA, b1, N, h1b);

    // Layer 2: [N,256]@[256,256]
    gemm_mfma<<<dim3(2, gy), blk, 0, stream>>>(h1b, Wl2t, nullptr, xlb, N, 256, 256, 0);
    gemm_mfma<<<dim3(2, gy), blk, 0, stream>>>(h1b, Wr2t, nullptr, xrb, N, 256, 256, 0);
    k_attn<<<(N + 3) / 4, blk, 0, stream>>>(xlb, xrb, att2, rowptr, colA, b2, N, h2b);

    // h3 = h2@W3 + b3  [N,256]@[256,128] -> f32
    gemm_mfma<<<dim3(1, gy), blk, 0, stream>>>(h2b, W3t, b3, h3f, N, 128, 256, 1);

    // out = sigmoid(h3@W4 + b4)  [N,128]@[128,40]
    gemm_f32<<<dim3(1, (N + BM - 1) / BM), blk, 0, stream>>>(h3f, W4, b4, out, N, 40, 128, 2);
}

// Round 4
// 331.249 us; speedup vs baseline: 3.3687x; 1.1752x over previous
//
#include <hip/hip_runtime.h>
#include <hip/hip_bf16.h>
#include <math.h>

typedef __attribute__((ext_vector_type(4))) float f32x4;
typedef __attribute__((ext_vector_type(8))) short s16x8;
typedef __attribute__((ext_vector_type(8))) unsigned short u16x8;

__device__ inline unsigned short f2b(float f) {
    union { float f; unsigned u; } x; x.f = f;
    unsigned r = x.u + 0x7FFF + ((x.u >> 16) & 1);   // RNE
    return (unsigned short)(r >> 16);
}
__device__ inline float b2f(unsigned short b) {
    union { unsigned u; float f; } x; x.u = ((unsigned)b) << 16; return x.f;
}

__device__ inline void gload_lds16(const void* g, void* l) {
    __builtin_amdgcn_global_load_lds(
        (const __attribute__((address_space(1))) void*)g,
        (__attribute__((address_space(3))) void*)l, 16, 0, 0);
}

// ---------------- bf16 MFMA GEMM ----------------
// A [M,K] bf16 row-major, Bt [Nn,K] bf16 row-major (B pre-transposed).
// mode 0: bf16 out, split-write: col<split -> C (stride split), else C2 (stride Nn-split).
// mode 1: f32 out + bias (split must equal Nn).
#define GBM 128
#define GBN 128
#define GBK 64

__global__ __launch_bounds__(256) void gemm_mfma(
    const unsigned short* __restrict__ A, const unsigned short* __restrict__ Bt,
    const float* __restrict__ bias, void* __restrict__ Cout, void* __restrict__ Cout2,
    int M, int Nn, int K, int split, int mode)
{
    __shared__ unsigned short As[GBM * GBK];
    __shared__ unsigned short Bs[GBN * GBK];
    const int tid = threadIdx.x;
    const int lane = tid & 63;
    const int w = tid >> 6, wm = w >> 1, wn = w & 1;
    const int row0 = blockIdx.y * GBM, col0 = blockIdx.x * GBN;
    const int l15 = lane & 15, l7 = lane & 7, lhi = lane >> 4;

    f32x4 acc[4][4] = {};

    for (int k0 = 0; k0 < K; k0 += GBK) {
        #pragma unroll
        for (int i = 0; i < 4; i++) {               // A: 1024 chunks of 16B
            int L = i * 256 + tid;
            int row = L >> 3;
            int c = (L & 7) ^ (row & 7);
            int gr = row0 + row; gr = gr < M ? gr : M - 1;
            gload_lds16(A + (size_t)gr * K + k0 + c * 8, (char*)As + L * 16);
        }
        #pragma unroll
        for (int i = 0; i < 4; i++) {               // B: 1024 chunks
            int L = i * 256 + tid;
            int row = L >> 3;
            int c = (L & 7) ^ (row & 7);
            gload_lds16(Bt + (size_t)(col0 + row) * K + k0 + c * 8, (char*)Bs + L * 16);
        }
        __syncthreads();                            // drains vmcnt too
        #pragma unroll
        for (int kk = 0; kk < 2; kk++) {
            s16x8 af[4], bf[4];
            #pragma unroll
            for (int i = 0; i < 4; i++) {
                int slot = (wm * 64 + i * 16 + l15) * 8 + ((kk * 4 + lhi) ^ l7);
                af[i] = *(const s16x8*)((const char*)As + slot * 16);
            }
            #pragma unroll
            for (int j = 0; j < 4; j++) {
                int slot = (wn * 64 + j * 16 + l15) * 8 + ((kk * 4 + lhi) ^ l7);
                bf[j] = *(const s16x8*)((const char*)Bs + slot * 16);
            }
            #pragma unroll
            for (int i = 0; i < 4; i++)
                #pragma unroll
                for (int j = 0; j < 4; j++)
                    acc[i][j] = __builtin_amdgcn_mfma_f32_16x16x32_bf16(
                        af[i], bf[j], acc[i][j], 0, 0, 0);
        }
        __syncthreads();
    }

    // epilogue: C/D layout col=lane&15, row=(lane>>4)*4+reg (m89-verified)
    if (mode == 0) {
        unsigned short* C  = (unsigned short*)Cout;
        unsigned short* C2 = (unsigned short*)Cout2;
        const int ld2 = Nn - split;
        #pragma unroll
        for (int i = 0; i < 4; i++)
            #pragma unroll
            for (int r = 0; r < 4; r++) {
                int row = row0 + wm * 64 + i * 16 + lhi * 4 + r;
                if (row >= M) continue;
                #pragma unroll
                for (int j = 0; j < 4; j++) {
                    int col = col0 + wn * 64 + j * 16 + l15;
                    unsigned short val = f2b(acc[i][j][r]);
                    if (col < split) C[(size_t)row * split + col] = val;
                    else             C2[(size_t)row * ld2 + (col - split)] = val;
                }
            }
    } else {
        float* C = (float*)Cout;
        #pragma unroll
        for (int i = 0; i < 4; i++)
            #pragma unroll
            for (int r = 0; r < 4; r++) {
                int row = row0 + wm * 64 + i * 16 + lhi * 4 + r;
                if (row >= M) continue;
                #pragma unroll
                for (int j = 0; j < 4; j++) {
                    int col = col0 + wn * 64 + j * 16 + l15;
                    C[(size_t)row * Nn + col] = acc[i][j][r] + bias[col];
                }
            }
    }
}

// ---------------- f32 GEMM (only for final W4, N=40) ----------------
#define BM 64
#define BN 64
#define BKK 16
__global__ __launch_bounds__(256) void gemm_f32(const float* __restrict__ A,
    const float* __restrict__ B, const float* __restrict__ bias,
    float* __restrict__ C, int M, int N, int K, int act)
{
    __shared__ float As[BKK][BM + 4];
    __shared__ float Bs[BKK][BN + 4];
    const int tid = threadIdx.x;
    const int tx = tid & 15, ty = tid >> 4;
    const int row0 = blockIdx.y * BM, col0 = blockIdx.x * BN;

    float acc[4][4] = {};

    for (int k0 = 0; k0 < K; k0 += BKK) {
        #pragma unroll
        for (int i = 0; i < 4; i++) {
            int idx = tid + i * 256;
            int am = idx >> 4;
            int ak = idx & 15;
            int gr = row0 + am;
            As[ak][am] = (gr < M) ? A[(size_t)gr * K + k0 + ak] : 0.f;
        }
        #pragma unroll
        for (int i = 0; i < 4; i++) {
            int idx = tid + i * 256;
            int bk = idx >> 6;
            int bn = idx & 63;
            int gc = col0 + bn;
            Bs[bk][bn] = (gc < N) ? B[(size_t)(k0 + bk) * N + gc] : 0.f;
        }
        __syncthreads();
        #pragma unroll
        for (int kk = 0; kk < BKK; kk++) {
            float4 a4 = *(const float4*)&As[kk][ty * 4];
            float4 b4 = *(const float4*)&Bs[kk][tx * 4];
            float av[4] = {a4.x, a4.y, a4.z, a4.w};
            float bv[4] = {b4.x, b4.y, b4.z, b4.w};
            #pragma unroll
            for (int i = 0; i < 4; i++)
                #pragma unroll
                for (int j = 0; j < 4; j++)
                    acc[i][j] += av[i] * bv[j];
        }
        __syncthreads();
    }

    #pragma unroll
    for (int i = 0; i < 4; i++) {
        int r = row0 + ty * 4 + i;
        if (r >= M) continue;
        #pragma unroll
        for (int j = 0; j < 4; j++) {
            int c = col0 + tx * 4 + j;
            if (c >= N) continue;
            float v = acc[i][j] + (bias ? bias[c] : 0.f);
            if (act == 2) v = 1.f / (1.f + expf(-v));
            C[(size_t)r * N + c] = v;
        }
    }
}

// ---------------- conversions ----------------
__global__ void k_cvt4(const float* __restrict__ in, unsigned short* __restrict__ out, int n4) {
    int i = blockIdx.x * 256 + threadIdx.x;
    if (i >= n4) return;
    float4 v = *(const float4*)&in[i * 4];
    ushort4 o = { f2b(v.x), f2b(v.y), f2b(v.z), f2b(v.w) };
    *(ushort4*)&out[i * 4] = o;
}
// out[n*K+k] = bf16(in[k*N+n])  (weight [K,N] -> [N,K] bf16)
__global__ void k_cvt_t(const float* __restrict__ in, unsigned short* __restrict__ out,
                        int K, int N) {
    int i = blockIdx.x * 256 + threadIdx.x;
    if (i >= K * N) return;
    int n = i / K, k = i - n * K;
    out[i] = f2b(in[(size_t)k * N + n]);
}

// ---------------- CSR build ----------------
__global__ void k_zero(int* __restrict__ p, int n) {
    int i = blockIdx.x * blockDim.x + threadIdx.x;
    if (i < n) p[i] = 0;
}
__global__ void k_count(const int* __restrict__ dstv, int E, int* __restrict__ deg) {
    int e = blockIdx.x * blockDim.x + threadIdx.x;
    if (e < E) atomicAdd(&deg[dstv[e]], 1);
}
__global__ __launch_bounds__(256) void k_scan1(const int* __restrict__ deg, int n,
    int* __restrict__ incl, int* __restrict__ bsum)
{
    __shared__ int s[256];
    int tid = threadIdx.x;
    int i = blockIdx.x * 256 + tid;
    s[tid] = (i < n) ? deg[i] : 0;
    __syncthreads();
    for (int off = 1; off < 256; off <<= 1) {
        int t = (tid >= off) ? s[tid - off] : 0;
        __syncthreads();
        s[tid] += t;
        __syncthreads();
    }
    if (i < n) incl[i] = s[tid];
    if (tid == 255) bsum[blockIdx.x] = s[255];
}
__global__ __launch_bounds__(256) void k_scan2(const int* __restrict__ bsum, int nc,
    int* __restrict__ bscan)
{
    __shared__ int s[256];
    int tid = threadIdx.x;
    s[tid] = (tid < nc) ? bsum[tid] : 0;
    __syncthreads();
    for (int off = 1; off < 256; off <<= 1) {
        int t = (tid >= off) ? s[tid - off] : 0;
        __syncthreads();
        s[tid] += t;
        __syncthreads();
    }
    bscan[tid] = s[tid];
}
__global__ void k_scan3(const int* __restrict__ deg, const int* __restrict__ incl,
    const int* __restrict__ bscan, int n, int* __restrict__ rowptr, int* __restrict__ cursor)
{
    int i = blockIdx.x * blockDim.x + threadIdx.x;
    if (i >= n) return;
    int c = i >> 8;
    int off = (c > 0) ? bscan[c - 1] : 0;
    int inc = incl[i] + off;
    rowptr[i + 1] = inc;
    cursor[i] = inc - deg[i];
    if (i == 0) rowptr[0] = 0;
}
__global__ void k_fill(const int* __restrict__ src, const int* __restrict__ dstv, int E,
    int* __restrict__ cursor, int* __restrict__ colA)
{
    int e = blockIdx.x * blockDim.x + threadIdx.x;
    if (e >= E) return;
    int d = dstv[e];
    int slot = atomicAdd(&cursor[d], 1);
    colA[slot] = src[e];
}

// ---------------- fused attention v3 ----------------
// One wave per dst node; two independent edge streams (one per 32-lane half),
// each lane holds 8 channels (16B ushort8 gathers). Unroll x2 per stream ->
// 4 independent gathers in flight per wave. Streams merged at the end via
// shfl_xor(32). Head = (lane&31)>>4; dot reduce = 4 shuffles over 16 lanes.
__global__ __launch_bounds__(256) void k_attn(const unsigned short* __restrict__ xl,
    const unsigned short* __restrict__ xr, const float* __restrict__ att,
    const int* __restrict__ rowptr, const int* __restrict__ colA,
    const float* __restrict__ bias, int Nn, unsigned short* __restrict__ outp)
{
    int n = blockIdx.x * 4 + (threadIdx.x >> 6);
    int lane = threadIdx.x & 63;
    if (n >= Nn) return;
    const int lh = lane & 31;        // lane-in-half: channels lh*8 .. lh*8+7
    const int h  = lane >> 5;        // edge-stream id
    int r0 = rowptr[n], r1 = rowptr[n + 1];

    u16x8 xb = *(const u16x8*)&xr[(size_t)n * 256 + lh * 8];
    float xrv[8], w[8];
    #pragma unroll
    for (int k = 0; k < 8; k++) { xrv[k] = b2f(xb[k]); w[k] = att[lh * 8 + k]; }

    float m = -INFINITY, l = 0.f;
    float acc[8] = {};

    auto update = [&](const u16x8& vb) {
        float v[8];
        #pragma unroll
        for (int k = 0; k < 8; k++) v[k] = b2f(vb[k]);
        float dot = 0.f;
        #pragma unroll
        for (int k = 0; k < 8; k++) {
            float t = v[k] + xrv[k];
            t = t > 0.f ? t : 0.2f * t;
            dot += t * w[k];
        }
        #pragma unroll
        for (int off = 1; off <= 8; off <<= 1) dot += __shfl_xor(dot, off);
        // dot uniform within each 16-lane head group
        float mn = fmaxf(m, dot);
        float sc = __expf(m - mn);
        float we = __expf(dot - mn);
        l = l * sc + we;
        #pragma unroll
        for (int k = 0; k < 8; k++) acc[k] = acc[k] * sc + we * v[k];
        m = mn;
    };

    int s = r0 + h;
    for (; s + 2 < r1; s += 4) {
        int c0 = colA[s], c1 = colA[s + 2];
        u16x8 v0 = *(const u16x8*)&xl[(size_t)c0 * 256 + lh * 8];
        u16x8 v1 = *(const u16x8*)&xl[(size_t)c1 * 256 + lh * 8];
        update(v0);
        update(v1);
    }
    for (; s < r1; s += 2) {
        int c = colA[s];
        u16x8 v = *(const u16x8*)&xl[(size_t)c * 256 + lh * 8];
        update(v);
    }

    // merge the two half-wave streams (lane i <-> lane i^32 hold same channels)
    float mo = __shfl_xor(m, 32);
    float lo = __shfl_xor(l, 32);
    float ms = fmaxf(m, mo);
    float es = __expf(m - ms), eo = __expf(mo - ms);
    float lt = l * es + lo * eo + 1e-16f;
    float inv = 1.f / lt;

    u16x8 o;
    #pragma unroll
    for (int k = 0; k < 8; k++) {
        float other = __shfl_xor(acc[k], 32);
        float r = (acc[k] * es + other * eo) * inv + bias[lh * 8 + k];
        o[k] = f2b(fmaxf(r, 0.f));
    }
    if (h == 0) *(u16x8*)&outp[(size_t)n * 256 + lh * 8] = o;
}

// ---------------- launch ----------------
extern "C" void kernel_launch(void* const* d_in, const int* in_sizes, int n_in,
                              void* d_out, int out_size, void* d_ws, size_t ws_size,
                              hipStream_t stream)
{
    const float* x    = (const float*)d_in[0];
    const int*   ei   = (const int*)d_in[1];
    const float* Wl1  = (const float*)d_in[2];
    const float* Wr1  = (const float*)d_in[3];
    const float* att1 = (const float*)d_in[4];
    const float* b1   = (const float*)d_in[5];
    const float* Wl2  = (const float*)d_in[6];
    const float* Wr2  = (const float*)d_in[7];
    const float* att2 = (const float*)d_in[8];
    const float* b2   = (const float*)d_in[9];
    const float* W3   = (const float*)d_in[10];
    const float* b3   = (const float*)d_in[11];
    const float* W4   = (const float*)d_in[12];
    const float* b4   = (const float*)d_in[13];

    const int N = in_sizes[0] / 128;       // 50000
    const int E = in_sizes[1] / 2;         // 650000
    const int* src  = ei;
    const int* dstv = ei + E;
    float* out = (float*)d_out;

    char* ws = (char*)d_ws;
    size_t o = 0;
    auto alloc = [&](size_t bytes) -> void* {
        void* p = ws + o;
        o += (bytes + 255) & ~(size_t)255;
        return p;
    };
    unsigned short* xbf    = (unsigned short*)alloc((size_t)N * 128 * 2);
    unsigned short* Wcat1  = (unsigned short*)alloc(512 * 128 * 2);  // [Wl1;Wr1]^T
    unsigned short* Wcat2  = (unsigned short*)alloc(512 * 256 * 2);  // [Wl2;Wr2]^T
    unsigned short* W3t    = (unsigned short*)alloc(128 * 256 * 2);
    unsigned short* xlb    = (unsigned short*)alloc((size_t)N * 256 * 2);
    unsigned short* xrb    = (unsigned short*)alloc((size_t)N * 256 * 2);
    unsigned short* h1b    = (unsigned short*)alloc((size_t)N * 256 * 2);
    unsigned short* h2b    = (unsigned short*)alloc((size_t)N * 256 * 2);
    float*          h3f    = (float*)alloc((size_t)N * 128 * 4);
    int* deg    = (int*)alloc((size_t)N * 4);
    int* incl   = (int*)alloc((size_t)N * 4);
    int* rowptr = (int*)alloc((size_t)(N + 1) * 4);
    int* cursor = (int*)alloc((size_t)N * 4);
    int* bsum   = (int*)alloc(1024);
    int* bscan  = (int*)alloc(1024);
    int* colA   = (int*)alloc((size_t)E * 4);

    const int nchunk = (N + 255) / 256;    // 196
    dim3 blk(256);

    // conversions (Wcat: first 256 rows from Wl, next 256 from Wr)
    k_cvt4<<<(N * 128 / 4 + 255) / 256, blk, 0, stream>>>(x, xbf, N * 128 / 4);
    k_cvt_t<<<(128 * 256 + 255) / 256, blk, 0, stream>>>(Wl1, Wcat1, 128, 256);
    k_cvt_t<<<(128 * 256 + 255) / 256, blk, 0, stream>>>(Wr1, Wcat1 + 256 * 128, 128, 256);
    k_cvt_t<<<(256 * 256 + 255) / 256, blk, 0, stream>>>(Wl2, Wcat2, 256, 256);
    k_cvt_t<<<(256 * 256 + 255) / 256, blk, 0, stream>>>(Wr2, Wcat2 + 256 * 256, 256, 256);
    k_cvt_t<<<(256 * 128 + 255) / 256, blk, 0, stream>>>(W3, W3t, 256, 128);

    // CSR build (by dst)
    k_zero<<<(N + 255) / 256, blk, 0, stream>>>(deg, N);
    k_count<<<(E + 255) / 256, blk, 0, stream>>>(dstv, E, deg);
    k_scan1<<<nchunk, blk, 0, stream>>>(deg, N, incl, bsum);
    k_scan2<<<1, blk, 0, stream>>>(bsum, nchunk, bscan);
    k_scan3<<<(N + 255) / 256, blk, 0, stream>>>(deg, incl, bscan, N, rowptr, cursor);
    k_fill<<<(E + 255) / 256, blk, 0, stream>>>(src, dstv, E, cursor, colA);

    const int gy = (N + GBM - 1) / GBM;    // 391

    // Layer 1: [xl|xr] = x @ [Wl1|Wr1]   [N,128]@[128,512], split-write
    gemm_mfma<<<dim3(4, gy), blk, 0, stream>>>(xbf, Wcat1, nullptr, xlb, xrb,
                                               N, 512, 128, 256, 0);
    k_attn<<<(N + 3) / 4, blk, 0, stream>>>(xlb, xrb, att1, rowptr, colA, b1, N, h1b);

    // Layer 2: [N,256]@[256,512], split-write
    gemm_mfma<<<dim3(4, gy), blk, 0, stream>>>(h1b, Wcat2, nullptr, xlb, xrb,
                                               N, 512, 256, 256, 0);
    k_attn<<<(N + 3) / 4, blk, 0, stream>>>(xlb, xrb, att2, rowptr, colA, b2, N, h2b);

    // h3 = h2@W3 + b3  [N,256]@[256,128] -> f32
    gemm_mfma<<<dim3(1, gy), blk, 0, stream>>>(h2b, W3t, b3, h3f, nullptr,
                                               N, 128, 256, 128, 1);

    // out = sigmoid(h3@W4 + b4)  [N,128]@[128,40]
    gemm_f32<<<dim3(1, (N + BM - 1) / BM), blk, 0, stream>>>(h3f, W4, b4, out, N, 40, 128, 2);
}

// Round 6
// 318.858 us; speedup vs baseline: 3.4996x; 1.0389x over previous
//
#include <hip/hip_runtime.h>
#include <hip/hip_bf16.h>
#include <math.h>

typedef __attribute__((ext_vector_type(4))) float f32x4;
typedef __attribute__((ext_vector_type(8))) short s16x8;
typedef __attribute__((ext_vector_type(8))) unsigned short u16x8;

__device__ inline unsigned short f2b(float f) {
    union { float f; unsigned u; } x; x.f = f;
    unsigned r = x.u + 0x7FFF + ((x.u >> 16) & 1);   // RNE
    return (unsigned short)(r >> 16);
}
__device__ inline float b2f(unsigned short b) {
    union { unsigned u; float f; } x; x.u = ((unsigned)b) << 16; return x.f;
}

__device__ inline void gload_lds16(const void* g, void* l) {
    __builtin_amdgcn_global_load_lds(
        (const __attribute__((address_space(1))) void*)g,
        (__attribute__((address_space(3))) void*)l, 16, 0, 0);
}

// ---------------- bf16 MFMA GEMM ----------------
// A [M,K] bf16 row-major, Bt [Nn,K] bf16 row-major (B pre-transposed).
// mode 0: bf16 split write: col<split -> C (stride split), else C2 (stride Nn-split)
// mode 1: bf16 + bias -> C (stride Nn)
// mode 2: f32 + bias + sigmoid -> C, only col<split stored, stride split
#define GBM 128
#define GBN 128
#define GBK 64

__global__ __launch_bounds__(256) void gemm_mfma(
    const unsigned short* __restrict__ A, const unsigned short* __restrict__ Bt,
    const float* __restrict__ bias, void* __restrict__ Cout, void* __restrict__ Cout2,
    int M, int Nn, int K, int split, int mode)
{
    __shared__ unsigned short As[GBM * GBK];
    __shared__ unsigned short Bs[GBN * GBK];
    const int tid = threadIdx.x;
    const int lane = tid & 63;
    const int w = tid >> 6, wm = w >> 1, wn = w & 1;
    const int row0 = blockIdx.y * GBM, col0 = blockIdx.x * GBN;
    const int l15 = lane & 15, l7 = lane & 7, lhi = lane >> 4;

    f32x4 acc[4][4] = {};

    for (int k0 = 0; k0 < K; k0 += GBK) {
        #pragma unroll
        for (int i = 0; i < 4; i++) {               // A: 1024 chunks of 16B
            int L = i * 256 + tid;
            int row = L >> 3;
            int c = (L & 7) ^ (row & 7);
            int gr = row0 + row; gr = gr < M ? gr : M - 1;
            gload_lds16(A + (size_t)gr * K + k0 + c * 8, (char*)As + L * 16);
        }
        #pragma unroll
        for (int i = 0; i < 4; i++) {               // B: 1024 chunks
            int L = i * 256 + tid;
            int row = L >> 3;
            int c = (L & 7) ^ (row & 7);
            gload_lds16(Bt + (size_t)(col0 + row) * K + k0 + c * 8, (char*)Bs + L * 16);
        }
        __syncthreads();                            // drains vmcnt too
        #pragma unroll
        for (int kk = 0; kk < 2; kk++) {
            s16x8 af[4], bf[4];
            #pragma unroll
            for (int i = 0; i < 4; i++) {
                int slot = (wm * 64 + i * 16 + l15) * 8 + ((kk * 4 + lhi) ^ l7);
                af[i] = *(const s16x8*)((const char*)As + slot * 16);
            }
            #pragma unroll
            for (int j = 0; j < 4; j++) {
                int slot = (wn * 64 + j * 16 + l15) * 8 + ((kk * 4 + lhi) ^ l7);
                bf[j] = *(const s16x8*)((const char*)Bs + slot * 16);
            }
            #pragma unroll
            for (int i = 0; i < 4; i++)
                #pragma unroll
                for (int j = 0; j < 4; j++)
                    acc[i][j] = __builtin_amdgcn_mfma_f32_16x16x32_bf16(
                        af[i], bf[j], acc[i][j], 0, 0, 0);
        }
        __syncthreads();
    }

    // epilogue: C/D layout col=lane&15, row=(lane>>4)*4+reg (m89-verified)
    if (mode == 0) {
        unsigned short* C  = (unsigned short*)Cout;
        unsigned short* C2 = (unsigned short*)Cout2;
        const int ld2 = Nn - split;
        #pragma unroll
        for (int i = 0; i < 4; i++)
            #pragma unroll
            for (int r = 0; r < 4; r++) {
                int row = row0 + wm * 64 + i * 16 + lhi * 4 + r;
                if (row >= M) continue;
                #pragma unroll
                for (int j = 0; j < 4; j++) {
                    int col = col0 + wn * 64 + j * 16 + l15;
                    unsigned short val = f2b(acc[i][j][r]);
                    if (col < split) C[(size_t)row * split + col] = val;
                    else             C2[(size_t)row * ld2 + (col - split)] = val;
                }
            }
    } else if (mode == 1) {
        unsigned short* C = (unsigned short*)Cout;
        #pragma unroll
        for (int i = 0; i < 4; i++)
            #pragma unroll
            for (int r = 0; r < 4; r++) {
                int row = row0 + wm * 64 + i * 16 + lhi * 4 + r;
                if (row >= M) continue;
                #pragma unroll
                for (int j = 0; j < 4; j++) {
                    int col = col0 + wn * 64 + j * 16 + l15;
                    C[(size_t)row * Nn + col] = f2b(acc[i][j][r] + bias[col]);
                }
            }
    } else {
        float* C = (float*)Cout;
        #pragma unroll
        for (int i = 0; i < 4; i++)
            #pragma unroll
            for (int r = 0; r < 4; r++) {
                int row = row0 + wm * 64 + i * 16 + lhi * 4 + r;
                if (row >= M) continue;
                #pragma unroll
                for (int j = 0; j < 4; j++) {
                    int col = col0 + wn * 64 + j * 16 + l15;
                    if (col >= split) continue;
                    float v = acc[i][j][r] + bias[col];
                    C[(size_t)row * split + col] = 1.f / (1.f + __expf(-v));
                }
            }
    }
}

// ---------------- conversions ----------------
__global__ void k_cvt4(const float* __restrict__ in, unsigned short* __restrict__ out, int n4) {
    int i = blockIdx.x * 256 + threadIdx.x;
    if (i >= n4) return;
    float4 v = *(const float4*)&in[i * 4];
    ushort4 o = { f2b(v.x), f2b(v.y), f2b(v.z), f2b(v.w) };
    *(ushort4*)&out[i * 4] = o;
}

// all weight transposes+casts in ONE launch; segment by blockIdx.y
__global__ void k_cvt_w(const float* __restrict__ Wl1, const float* __restrict__ Wr1,
                        const float* __restrict__ Wl2, const float* __restrict__ Wr2,
                        const float* __restrict__ W3,  const float* __restrict__ W4,
                        unsigned short* __restrict__ Wcat1, unsigned short* __restrict__ Wcat2,
                        unsigned short* __restrict__ W3t,   unsigned short* __restrict__ W4t)
{
    int i = blockIdx.x * 256 + threadIdx.x;
    switch (blockIdx.y) {
    case 0: if (i < 32768) { int n = i >> 7, k = i & 127; Wcat1[i] = f2b(Wl1[k * 256 + n]); } break;
    case 1: if (i < 32768) { int n = i >> 7, k = i & 127; Wcat1[32768 + i] = f2b(Wr1[k * 256 + n]); } break;
    case 2: if (i < 65536) { int n = i >> 8, k = i & 255; Wcat2[i] = f2b(Wl2[k * 256 + n]); } break;
    case 3: if (i < 65536) { int n = i >> 8, k = i & 255; Wcat2[65536 + i] = f2b(Wr2[k * 256 + n]); } break;
    case 4: if (i < 32768) { int n = i >> 8, k = i & 255; W3t[i] = f2b(W3[k * 128 + n]); } break;
    case 5: if (i < 16384) { int n = i >> 7, k = i & 127; W4t[i] = (n < 40) ? f2b(W4[k * 40 + n]) : 0; } break;
    }
}

// ---------------- CSR build ----------------
__global__ void k_count(const int* __restrict__ dstv, int E, int* __restrict__ deg) {
    int e = blockIdx.x * blockDim.x + threadIdx.x;
    if (e < E) atomicAdd(&deg[dstv[e]], 1);
}
__global__ __launch_bounds__(256) void k_scan1(const int* __restrict__ deg, int n,
    int* __restrict__ incl, int* __restrict__ bsum)
{
    __shared__ int s[256];
    int tid = threadIdx.x;
    int i = blockIdx.x * 256 + tid;
    s[tid] = (i < n) ? deg[i] : 0;
    __syncthreads();
    for (int off = 1; off < 256; off <<= 1) {
        int t = (tid >= off) ? s[tid - off] : 0;
        __syncthreads();
        s[tid] += t;
        __syncthreads();
    }
    if (i < n) incl[i] = s[tid];
    if (tid == 255) bsum[blockIdx.x] = s[255];
}
__global__ __launch_bounds__(256) void k_scan2(const int* __restrict__ bsum, int nc,
    int* __restrict__ bscan)
{
    __shared__ int s[256];
    int tid = threadIdx.x;
    s[tid] = (tid < nc) ? bsum[tid] : 0;
    __syncthreads();
    for (int off = 1; off < 256; off <<= 1) {
        int t = (tid >= off) ? s[tid - off] : 0;
        __syncthreads();
        s[tid] += t;
        __syncthreads();
    }
    bscan[tid] = s[tid];
}
__global__ void k_scan3(const int* __restrict__ deg, const int* __restrict__ incl,
    const int* __restrict__ bscan, int n, int* __restrict__ rowptr, int* __restrict__ cursor)
{
    int i = blockIdx.x * blockDim.x + threadIdx.x;
    if (i >= n) return;
    int c = i >> 8;
    int off = (c > 0) ? bscan[c - 1] : 0;
    int inc = incl[i] + off;
    rowptr[i + 1] = inc;
    cursor[i] = inc - deg[i];
    if (i == 0) rowptr[0] = 0;
}
__global__ void k_fill(const int* __restrict__ src, const int* __restrict__ dstv, int E,
    int* __restrict__ cursor, int* __restrict__ colA)
{
    int e = blockIdx.x * blockDim.x + threadIdx.x;
    if (e >= E) return;
    int d = dstv[e];
    int slot = atomicAdd(&cursor[d], 1);
    colA[slot] = src[e];
}

// ---------------- fused attention v4 ----------------
// One wave per dst node; two edge streams (one per 32-lane half), lane holds
// 8 channels (16B gathers), unroll x2 -> 4 gathers in flight. Scores kept in
// exp2 domain (log2e folded into att). Defer-max (THR=8): fast path does
// single-FMA accumulate + one exp2; rescale only when ballot sees dot>m+8.
__global__ __launch_bounds__(256) void k_attn(const unsigned short* __restrict__ xl,
    const unsigned short* __restrict__ xr, const float* __restrict__ att,
    const int* __restrict__ rowptr, const int* __restrict__ colA,
    const float* __restrict__ bias, int Nn, unsigned short* __restrict__ outp)
{
    int n = blockIdx.x * 4 + (threadIdx.x >> 6);
    int lane = threadIdx.x & 63;
    if (n >= Nn) return;
    const int lh = lane & 31;        // lane-in-half: channels lh*8 .. lh*8+7
    const int h  = lane >> 5;        // edge-stream id
    int r0 = rowptr[n], r1 = rowptr[n + 1];

    const float LOG2E = 1.4426950408889634f;
    u16x8 xb = *(const u16x8*)&xr[(size_t)n * 256 + lh * 8];
    float xrv[8], w[8];
    #pragma unroll
    for (int k = 0; k < 8; k++) { xrv[k] = b2f(xb[k]); w[k] = att[lh * 8 + k] * LOG2E; }

    float m = -INFINITY, l = 0.f;
    float acc[8] = {};

    auto update = [&](const u16x8& vb) {
        float v[8];
        #pragma unroll
        for (int k = 0; k < 8; k++) v[k] = b2f(vb[k]);
        float dot = 0.f;
        #pragma unroll
        for (int k = 0; k < 8; k++) {
            float t = v[k] + xrv[k];
            t = fmaxf(t, 0.2f * t);          // leaky_relu, slope<1
            dot = fmaf(t, w[k], dot);
        }
        #pragma unroll
        for (int off = 1; off <= 8; off <<= 1) dot += __shfl_xor(dot, off);
        // dot uniform within each 16-lane head group, exp2 domain
        if (__ballot(dot > m + 8.f)) {       // rare rescale path
            float mn = fmaxf(m, dot);
            float sc = exp2f(m - mn);        // 0 on first edge (m=-inf)
            float we = exp2f(dot - mn);
            l = l * sc + we;
            #pragma unroll
            for (int k = 0; k < 8; k++) acc[k] = acc[k] * sc + we * v[k];
            m = mn;
        } else {                              // fast path: we <= 2^8
            float we = exp2f(dot - m);
            l += we;
            #pragma unroll
            for (int k = 0; k < 8; k++) acc[k] = fmaf(we, v[k], acc[k]);
        }
    };

    int s = r0 + h;
    for (; s + 2 < r1; s += 4) {
        int c0 = colA[s], c1 = colA[s + 2];
        u16x8 v0 = *(const u16x8*)&xl[(size_t)c0 * 256 + lh * 8];
        u16x8 v1 = *(const u16x8*)&xl[(size_t)c1 * 256 + lh * 8];
        update(v0);
        update(v1);
    }
    for (; s < r1; s += 2) {
        int c = colA[s];
        u16x8 v = *(const u16x8*)&xl[(size_t)c * 256 + lh * 8];
        update(v);
    }

    // merge the two half-wave streams (lane i <-> lane i^32 hold same channels)
    float mo = __shfl_xor(m, 32);
    float lo = __shfl_xor(l, 32);
    float ms = fmaxf(m, mo);
    float es = exp2f(m - ms), eo = exp2f(mo - ms);
    float lt = l * es + lo * eo + 1e-16f;
    float inv = 1.f / lt;

    u16x8 o;
    #pragma unroll
    for (int k = 0; k < 8; k++) {
        float other = __shfl_xor(acc[k], 32);
        float r = (acc[k] * es + other * eo) * inv + bias[lh * 8 + k];
        o[k] = f2b(fmaxf(r, 0.f));
    }
    if (h == 0) *(u16x8*)&outp[(size_t)n * 256 + lh * 8] = o;
}

// ---------------- launch ----------------
extern "C" void kernel_launch(void* const* d_in, const int* in_sizes, int n_in,
                              void* d_out, int out_size, void* d_ws, size_t ws_size,
                              hipStream_t stream)
{
    const float* x    = (const float*)d_in[0];
    const int*   ei   = (const int*)d_in[1];
    const float* Wl1  = (const float*)d_in[2];
    const float* Wr1  = (const float*)d_in[3];
    const float* att1 = (const float*)d_in[4];
    const float* b1   = (const float*)d_in[5];
    const float* Wl2  = (const float*)d_in[6];
    const float* Wr2  = (const float*)d_in[7];
    const float* att2 = (const float*)d_in[8];
    const float* b2   = (const float*)d_in[9];
    const float* W3   = (const float*)d_in[10];
    const float* b3   = (const float*)d_in[11];
    const float* W4   = (const float*)d_in[12];
    const float* b4   = (const float*)d_in[13];

    const int N = in_sizes[0] / 128;       // 50000
    const int E = in_sizes[1] / 2;         // 650000
    const int* src  = ei;
    const int* dstv = ei + E;
    float* out = (float*)d_out;

    char* ws = (char*)d_ws;
    size_t o = 0;
    auto alloc = [&](size_t bytes) -> void* {
        void* p = ws + o;
        o += (bytes + 255) & ~(size_t)255;
        return p;
    };
    unsigned short* xbf    = (unsigned short*)alloc((size_t)N * 128 * 2);
    unsigned short* Wcat1  = (unsigned short*)alloc(512 * 128 * 2);  // [Wl1;Wr1]^T
    unsigned short* Wcat2  = (unsigned short*)alloc(512 * 256 * 2);  // [Wl2;Wr2]^T
    unsigned short* W3t    = (unsigned short*)alloc(128 * 256 * 2);
    unsigned short* W4t    = (unsigned short*)alloc(128 * 128 * 2);  // N-padded to 128
    unsigned short* xlb    = (unsigned short*)alloc((size_t)N * 256 * 2);
    unsigned short* xrb    = (unsigned short*)alloc((size_t)N * 256 * 2);
    unsigned short* h1b    = (unsigned short*)alloc((size_t)N * 256 * 2);
    unsigned short* h2b    = (unsigned short*)alloc((size_t)N * 256 * 2);
    unsigned short* h3b    = (unsigned short*)alloc((size_t)N * 128 * 2);
    int* deg    = (int*)alloc((size_t)N * 4);
    int* incl   = (int*)alloc((size_t)N * 4);
    int* rowptr = (int*)alloc((size_t)(N + 1) * 4);
    int* cursor = (int*)alloc((size_t)N * 4);
    int* bsum   = (int*)alloc(1024);
    int* bscan  = (int*)alloc(1024);
    int* colA   = (int*)alloc((size_t)E * 4);

    const int nchunk = (N + 255) / 256;    // 196
    dim3 blk(256);

    // conversions
    k_cvt4<<<(N * 128 / 4 + 255) / 256, blk, 0, stream>>>(x, xbf, N * 128 / 4);
    k_cvt_w<<<dim3(256, 6), blk, 0, stream>>>(Wl1, Wr1, Wl2, Wr2, W3, W4,
                                              Wcat1, Wcat2, W3t, W4t);

    // CSR build (by dst)
    hipMemsetAsync(deg, 0, (size_t)N * 4, stream);
    k_count<<<(E + 255) / 256, blk, 0, stream>>>(dstv, E, deg);
    k_scan1<<<nchunk, blk, 0, stream>>>(deg, N, incl, bsum);
    k_scan2<<<1, blk, 0, stream>>>(bsum, nchunk, bscan);
    k_scan3<<<(N + 255) / 256, blk, 0, stream>>>(deg, incl, bscan, N, rowptr, cursor);
    k_fill<<<(E + 255) / 256, blk, 0, stream>>>(src, dstv, E, cursor, colA);

    const int gy = (N + GBM - 1) / GBM;    // 391

    // Layer 1: [xl|xr] = x @ [Wl1|Wr1]   [N,128]@[128,512], split-write
    gemm_mfma<<<dim3(4, gy), blk, 0, stream>>>(xbf, Wcat1, nullptr, xlb, xrb,
                                               N, 512, 128, 256, 0);
    k_attn<<<(N + 3) / 4, blk, 0, stream>>>(xlb, xrb, att1, rowptr, colA, b1, N, h1b);

    // Layer 2: [N,256]@[256,512], split-write
    gemm_mfma<<<dim3(4, gy), blk, 0, stream>>>(h1b, Wcat2, nullptr, xlb, xrb,
                                               N, 512, 256, 256, 0);
    k_attn<<<(N + 3) / 4, blk, 0, stream>>>(xlb, xrb, att2, rowptr, colA, b2, N, h2b);

    // h3 = bf16(h2@W3 + b3)  [N,256]@[256,128]
    gemm_mfma<<<dim3(1, gy), blk, 0, stream>>>(h2b, W3t, b3, h3b, nullptr,
                                               N, 128, 256, 128, 1);

    // out = sigmoid(h3@W4 + b4)  [N,128]@[128,40] via N-padded MFMA
    gemm_mfma<<<dim3(1, gy), blk, 0, stream>>>(h3b, W4t, b4, out, nullptr,
                                               N, 128, 128, 40, 2);
}